// Round 11
// baseline (359.652 us; speedup 1.0000x reference)
//
#include <hip/hip_runtime.h>
#include <math.h>

typedef __attribute__((ext_vector_type(8))) short short8;
typedef __attribute__((ext_vector_type(4))) float f32x4;
typedef __attribute__((ext_vector_type(4))) unsigned short us4;
typedef __attribute__((ext_vector_type(4))) unsigned int u32x4;
typedef __attribute__((ext_vector_type(4))) int i32x4;
typedef unsigned short u16;
typedef unsigned int u32;

#define LOG2E 1.4426950408889634f
// B=4, S=2048, E=1024, H=16, D=64, M=B*S=8192

static __device__ __forceinline__ u16 f2bf(float f){
  u32 u = __builtin_bit_cast(u32, f);
  u = (u + 0x7FFFu + ((u >> 16) & 1u)) >> 16;   // RTNE
  return (u16)u;
}
// NOTE: v_cvt_pk_bf16_f32 (and __float22bfloat162_rn) is NOT RTNE on gfx950 —
// using it for the P-pack cost 7e-3 absmax (rounds 2 & 5). Keep manual RTNE.
// NOTE2: 2-tile software pipeline (round 8) regressed 173->307us: VGPR spill
// (scratch WRITE 333MB) + lost block co-residency (FETCH 34->189MB). Use TLP.

static __device__ __forceinline__ void gload16(const void* g, void* l){
  __builtin_amdgcn_global_load_lds((const __attribute__((address_space(1))) void*)g,
                                   (__attribute__((address_space(3))) void*)l,
                                   16, 0, 0);
}

static __device__ __forceinline__ f32x4 mfma16(short8 a, short8 b, f32x4 c){
  return __builtin_amdgcn_mfma_f32_16x16x32_bf16(a, b, c, 0, 0, 0);
}

// ---------------- RoPE cos/sin table: [s][i], i = 0..31 ----------------
__global__ void rope_tab_k(float* __restrict__ cosT, float* __restrict__ sinT){
  int idx = blockIdx.x * 256 + threadIdx.x;   // 2048*32 = 65536
  int s = idx >> 5, i = idx & 31;
  double th = pow(10000.0, -((double)(2 * i)) / 64.0);
  float ang = (float)s * (float)th;           // fp32 rounding matches reference
  cosT[idx] = (float)cos((double)ang);
  sinT[idx] = (float)sin((double)ang);
}

// ---------------- x fp32 -> bf16 ----------------
__global__ void cvt_x_k(const float* __restrict__ x, u16* __restrict__ xb, int n){
  int i = (blockIdx.x * 256 + threadIdx.x) * 4;
  if (i >= n) return;
  f32x4 v = *(const f32x4*)(x + i);
  us4 o; o[0]=f2bf(v[0]); o[1]=f2bf(v[1]); o[2]=f2bf(v[2]); o[3]=f2bf(v[3]);
  *(us4*)(xb + i) = o;
}

// ---------------- W (k,n) fp32 -> WT (n,k) bf16, 4 matrices ----------------
__global__ void wt_cvt_k(const float* __restrict__ W0, const float* __restrict__ W1,
                         const float* __restrict__ W2, const float* __restrict__ W3,
                         u16* __restrict__ out){
  __shared__ float t[32][33];
  const float* W = (blockIdx.z == 0) ? W0 : (blockIdx.z == 1) ? W1 : (blockIdx.z == 2) ? W2 : W3;
  u16* O = out + (size_t)blockIdx.z * 1024 * 1024;
  int tx = threadIdx.x, ty = threadIdx.y;
  int kb = blockIdx.y * 32, nb = blockIdx.x * 32;
  #pragma unroll
  for (int i = 0; i < 4; i++)
    t[ty + i*8][tx] = W[(size_t)(kb + ty + i*8) * 1024 + nb + tx];
  __syncthreads();
  #pragma unroll
  for (int i = 0; i < 4; i++)
    O[(size_t)(nb + ty + i*8) * 1024 + kb + tx] = f2bf(t[tx][ty + i*8]);
}

// ---------------- fused QKV GEMM 8192x1024x1024 bf16 MFMA ----------------
__global__ __launch_bounds__(256, 2)
void qkv_gemm_k(const u16* __restrict__ A, const u16* __restrict__ WT,
                const float* __restrict__ bq, const float* __restrict__ bk,
                const float* __restrict__ bv,
                const float* __restrict__ cosT, const float* __restrict__ sinT,
                u16* __restrict__ Qr, u16* __restrict__ Kr, u16* __restrict__ Vt)
{
  __shared__ __align__(16) u16 Al[128][64];
  __shared__ __align__(16) u16 Bl[128][64];
  const int mode = blockIdx.y >> 3;
  const int cy   = blockIdx.y & 7;
  const u16* BT = WT + (size_t)mode * 1024 * 1024;
  const float* bias = (mode == 0) ? bq : (mode == 1) ? bk : bv;
  u16* outB = (mode == 0) ? Qr : (mode == 1) ? Kr : Vt;

  const int tid = threadIdx.x;
  const int w = tid >> 6, lane = tid & 63, g = lane >> 4, c = lane & 15;
  const int wr = w >> 1, wc = w & 1;
  const int R0 = blockIdx.x * 128, C0 = cy * 128;

  f32x4 acc[4][4];
  const f32x4 vz = {0.f, 0.f, 0.f, 0.f};
  #pragma unroll
  for (int mi = 0; mi < 4; mi++)
    #pragma unroll
    for (int ni = 0; ni < 4; ni++) acc[mi][ni] = vz;

  const u16* gA[4]; const u16* gB[4]; u16* lA[4]; u16* lB[4];
  #pragma unroll
  for (int i = 0; i < 4; i++){
    int I = w * 4 + i;
    int rr = I * 8 + (lane >> 3), kk = (lane & 7) * 8;
    gA[i] = A  + (size_t)(R0 + rr) * 1024 + kk;
    gB[i] = BT + (size_t)(C0 + rr) * 1024 + kk;
    lA[i] = &Al[I * 8][0];
    lB[i] = &Bl[I * 8][0];
  }

  for (int t = 0; t < 16; ++t){
    const int k0 = t * 64;
    #pragma unroll
    for (int i = 0; i < 4; i++){
      gload16(gA[i] + k0, lA[i]);
      gload16(gB[i] + k0, lB[i]);
    }
    __syncthreads();
    #pragma unroll
    for (int ki = 0; ki < 2; ++ki){
      short8 af[4], bfr[4];
      #pragma unroll
      for (int mi = 0; mi < 4; mi++) af[mi]  = *(const short8*)&Al[wr*64 + mi*16 + c][ki*32 + g*8];
      #pragma unroll
      for (int ni = 0; ni < 4; ni++) bfr[ni] = *(const short8*)&Bl[wc*64 + ni*16 + c][ki*32 + g*8];
      #pragma unroll
      for (int mi = 0; mi < 4; mi++)
        #pragma unroll
        for (int ni = 0; ni < 4; ni++)
          acc[mi][ni] = mfma16(af[mi], bfr[ni], acc[mi][ni]);
    }
    __syncthreads();
  }

  if (mode == 2){
    int h = cy * 2 + wc;
    #pragma unroll
    for (int ni = 0; ni < 4; ni++){
      int col = C0 + wc*64 + ni*16 + c;
      int d = ni*16 + c;
      float bvv = bias[col];
      #pragma unroll
      for (int mi = 0; mi < 4; mi++){
        int row0 = R0 + wr*64 + mi*16 + g*4;
        int b = row0 >> 11, s0 = row0 & 2047;
        us4 pk;
        #pragma unroll
        for (int r = 0; r < 4; r++) pk[r] = f2bf(acc[mi][ni][r] + bvv);
        *(us4*)&outB[((size_t)(b*16 + h)*64 + d)*2048 + s0] = pk;
      }
    }
  } else {
    int h = cy * 2 + wc;
    const float qs = (mode == 0) ? 0.125f : 1.0f;
    float bvv[4];
    #pragma unroll
    for (int ni = 0; ni < 4; ni++) bvv[ni] = bias[C0 + wc*64 + ni*16 + c];
    #pragma unroll
    for (int mi = 0; mi < 4; mi++){
      int row0 = R0 + wr*64 + mi*16 + g*4;
      int b = row0 >> 11;
      #pragma unroll
      for (int r = 0; r < 4; r++){
        int s = (row0 + r) & 2047;
        float v0 = acc[mi][0][r] + bvv[0];
        float v1 = acc[mi][1][r] + bvv[1];
        float v2 = acc[mi][2][r] + bvv[2];
        float v3 = acc[mi][3][r] + bvv[3];
        float ca = cosT[s*32 + c],      sa = sinT[s*32 + c];
        float cb = cosT[s*32 + 16 + c], sb = sinT[s*32 + 16 + c];
        float o0 = (v0*ca - v2*sa) * qs, o2 = (v2*ca + v0*sa) * qs;
        float o1 = (v1*cb - v3*sb) * qs, o3 = (v3*cb + v1*sb) * qs;
        size_t base = ((size_t)(b*16 + h)*2048 + s)*64;
        outB[base +  0 + c] = f2bf(o0);
        outB[base + 16 + c] = f2bf(o1);
        outB[base + 32 + c] = f2bf(o2);
        outB[base + 48 + c] = f2bf(o3);
      }
    }
  }
}

// ---------------- output GEMM (AO x Wo^T + bo -> fp32 out) ----------------
__global__ __launch_bounds__(256, 2)
void out_gemm_k(const u16* __restrict__ A, const u16* __restrict__ BT,
                const float* __restrict__ bias, float* __restrict__ outF)
{
  __shared__ __align__(16) u16 Al[128][64];
  __shared__ __align__(16) u16 Bl[128][64];
  const int tid = threadIdx.x;
  const int w = tid >> 6, lane = tid & 63, g = lane >> 4, c = lane & 15;
  const int wr = w >> 1, wc = w & 1;
  const int R0 = blockIdx.x * 128, C0 = blockIdx.y * 128;

  f32x4 acc[4][4];
  const f32x4 vz = {0.f, 0.f, 0.f, 0.f};
  #pragma unroll
  for (int mi = 0; mi < 4; mi++)
    #pragma unroll
    for (int ni = 0; ni < 4; ni++) acc[mi][ni] = vz;

  const u16* gA[4]; const u16* gB[4]; u16* lA[4]; u16* lB[4];
  #pragma unroll
  for (int i = 0; i < 4; i++){
    int I = w * 4 + i;
    int rr = I * 8 + (lane >> 3), kk = (lane & 7) * 8;
    gA[i] = A  + (size_t)(R0 + rr) * 1024 + kk;
    gB[i] = BT + (size_t)(C0 + rr) * 1024 + kk;
    lA[i] = &Al[I * 8][0];
    lB[i] = &Bl[I * 8][0];
  }

  for (int t = 0; t < 16; ++t){
    const int k0 = t * 64;
    #pragma unroll
    for (int i = 0; i < 4; i++){
      gload16(gA[i] + k0, lA[i]);
      gload16(gB[i] + k0, lB[i]);
    }
    __syncthreads();
    #pragma unroll
    for (int ki = 0; ki < 2; ++ki){
      short8 af[4], bfr[4];
      #pragma unroll
      for (int mi = 0; mi < 4; mi++) af[mi]  = *(const short8*)&Al[wr*64 + mi*16 + c][ki*32 + g*8];
      #pragma unroll
      for (int ni = 0; ni < 4; ni++) bfr[ni] = *(const short8*)&Bl[wc*64 + ni*16 + c][ki*32 + g*8];
      #pragma unroll
      for (int mi = 0; mi < 4; mi++)
        #pragma unroll
        for (int ni = 0; ni < 4; ni++)
          acc[mi][ni] = mfma16(af[mi], bfr[ni], acc[mi][ni]);
    }
    __syncthreads();
  }

  #pragma unroll
  for (int mi = 0; mi < 4; mi++){
    #pragma unroll
    for (int ni = 0; ni < 4; ni++){
      int col = C0 + wc*64 + ni*16 + c;
      float bvv = bias[col];
      int row0 = R0 + wr*64 + mi*16 + g*4;
      #pragma unroll
      for (int r = 0; r < 4; r++)
        outF[(size_t)(row0 + r) * 1024 + col] = acc[mi][ni][r] + bvv;
    }
  }
}

// ---------------- flash attention (K direct-to-reg, V via LDS) ----------------
// Q,K: (b,h,s,d) bf16 (Q pre-scaled by 0.125).  V: (b,h,d,s) bf16.
// out AO: (b,s,h,d) bf16.  512 threads = 8 waves, 16 q-rows each.
// K loads: per-lane 16B directly into A-fragment layout (pi folded into row base);
// lanes form 16 rows x 64B contiguous -> clean L2 sectors, no LDS staging for K.
// V: KVBLK=128 as 2 halves, LDS double-buffer (16-chunk XOR swizzle), 2 loads/wave.
// LDS 34KB -> 4 blocks/CU (grid 1024 = exactly 4/CU, no tail).
__global__ __launch_bounds__(512, 4)
void attn_fwd_k(const u16* __restrict__ Q, const u16* __restrict__ K, const u16* __restrict__ V,
                const int* __restrict__ msk, u16* __restrict__ AO)
{
  __shared__ __align__(16) u16 Vl[2][64][128];
  __shared__ __align__(8) unsigned char Ml[2048];
  const int tid = threadIdx.x;
  const int w = tid >> 6, lane = tid & 63, g = lane >> 4, c = lane & 15;

  // XCD-aware swizzle (bijective, 1024 = 8*128): XCD = lin%8 gets 8 full bh
  const int lin = blockIdx.y * 16 + blockIdx.x;
  const int v_  = (lin & 7) * 128 + (lin >> 3);
  const int bh = v_ >> 4, b = bh >> 4, h = bh & 15;
  const int qw = (v_ & 15) * 128 + w * 16;

  // Q B-fragments FIRST (2 global loads; drained by first vmcnt(2))
  short8 qb[2];
  #pragma unroll
  for (int ki = 0; ki < 2; ki++)
    qb[ki] = *(const short8*)&Q[((size_t)bh*2048 + qw + c)*64 + ki*32 + g*8];

  // V staging: 2 loads/wave, rows vr = w*8 + j*4 + (lane>>4), 16-chunk XOR swizzle
  const u16* gVs[2];
  #pragma unroll
  for (int j = 0; j < 2; j++){
    int vr = w*8 + j*4 + (lane >> 4);
    int lc = (lane & 15) ^ (vr & 15);            // logical t-chunk for this physical slot
    gVs[j] = V + ((size_t)bh*64 + vr)*2048 + lc*8;
  }
  // stage V tile 0 into buf 0
  #pragma unroll
  for (int j = 0; j < 2; j++) gload16(gVs[j], &Vl[0][w*8 + j*4][0]);

  // pack mask row for this b into LDS as u8 (0/1): 512 thr x 4 ints (1 VMEM load)
  {
    const int* mp = msk + b*2048 + tid*4;
    i32x4 a = *(const i32x4*)mp;
    u32 lo = (a[0] ? 1u : 0u) | (a[1] ? 0x100u : 0u) | (a[2] ? 0x10000u : 0u) | (a[3] ? 0x1000000u : 0u);
    *(u32*)&Ml[tid*4] = lo;
  }
  asm volatile("s_waitcnt lgkmcnt(0)" ::: "memory");  // Ml writes drained before first barrier

  // per-lane K fragment row bases: fragment row c of sub-tile nt <- logical row pi(nt*16+c)
  int rnt[4];
  #pragma unroll
  for (int nt = 0; nt < 4; nt++){
    int s = nt*16 + c;
    rnt[nt] = (s & 0x20) | ((s & 0x10) >> 2) | ((s & 0x0C) << 1) | (s & 3);  // pi(s)
  }
  const u16* Kg = K + (size_t)bh*2048*64 + g*8;   // + row*64 + ki*32 per load

  f32x4 oacc[4];
  float mrun = -1e30f, lrun = 0.f;
  const f32x4 vz = {0.f, 0.f, 0.f, 0.f};
  #pragma unroll
  for (int nd = 0; nd < 4; nd++) oacc[nd] = vz;

  for (int t = 0; t < 16; ++t){
    // stage V tile t+1 into buf (t+1)&1  (t=15 over-stage is harmless, in-ws)
    {
      const size_t vo = (size_t)(t+1) * 128;        // u16: 128 t's ahead
      #pragma unroll
      for (int j = 0; j < 2; j++) gload16(gVs[j] + vo, &Vl[(t+1)&1][w*8 + j*4][0]);
    }
    asm volatile("s_waitcnt vmcnt(2)" ::: "memory");  // V tile t drained; t+1 in flight
    __builtin_amdgcn_s_barrier();
    asm volatile("" ::: "memory");

    const u16* Vb = &Vl[t&1][0][0];

    #pragma unroll
    for (int half = 0; half < 2; ++half){
      const int t0 = t * 128 + half * 64;

      // S^T = K (A, direct from global) x Q (B): sacc[nt] = S[q=qw+c][t0+nt*16+4g+r]
      f32x4 sacc[4];
      #pragma unroll
      for (int nt = 0; nt < 4; nt++) sacc[nt] = vz;
      #pragma unroll
      for (int ki = 0; ki < 2; ki++){
        short8 ka[4];
        #pragma unroll
        for (int nt = 0; nt < 4; nt++)
          ka[nt] = *(const short8*)&Kg[(size_t)(t0 + rnt[nt])*64 + ki*32];
        #pragma unroll
        for (int nt = 0; nt < 4; nt++)
          sacc[nt] = mfma16(ka[nt], qb[ki], sacc[nt]);
      }

      // mask (u8): logical t of (nt,g,r) = t0 + 32*(nt>>1) + 8g + 4*(nt&1) + r
      {
        const u32 mw0 = *(const u32*)&Ml[t0 + 8*g];
        const u32 mw1 = *(const u32*)&Ml[t0 + 8*g + 4];
        const u32 mw2 = *(const u32*)&Ml[t0 + 32 + 8*g];
        const u32 mw3 = *(const u32*)&Ml[t0 + 32 + 8*g + 4];
        if (!__all((mw0 & mw1 & mw2 & mw3) == 0x01010101u)){
          const u32 mw[4] = {mw0, mw1, mw2, mw3};
          #pragma unroll
          for (int nt = 0; nt < 4; nt++)
            #pragma unroll
            for (int r = 0; r < 4; r++)
              if (((mw[nt] >> (8*r)) & 0xFFu) == 0) sacc[nt][r] = -1e9f;
        }
      }

      // tile max (tree) for row q = qw + c
      float a0 = fmaxf(fmaxf(sacc[0][0], sacc[0][1]), fmaxf(sacc[0][2], sacc[0][3]));
      float a1 = fmaxf(fmaxf(sacc[1][0], sacc[1][1]), fmaxf(sacc[1][2], sacc[1][3]));
      float a2 = fmaxf(fmaxf(sacc[2][0], sacc[2][1]), fmaxf(sacc[2][2], sacc[2][3]));
      float a3 = fmaxf(fmaxf(sacc[3][0], sacc[3][1]), fmaxf(sacc[3][2], sacc[3][3]));
      float pm = fmaxf(fmaxf(a0, a1), fmaxf(a2, a3));
      pm = fmaxf(pm, __shfl_xor(pm, 16, 64));
      pm = fmaxf(pm, __shfl_xor(pm, 32, 64));

      // defer-max: rescale only when max grew by > 8 (skip is EXACT when pm<=mrun)
      if (__any(pm > mrun + 8.f)){
        float mn = fmaxf(mrun, pm);
        float al = exp2f((mrun - mn) * LOG2E);
        mrun = mn;
        lrun *= al;                       // per-lane partial, al row-uniform
        float b0 = __shfl(al, g*4 + 0, 64);
        float b1 = __shfl(al, g*4 + 1, 64);
        float b2 = __shfl(al, g*4 + 2, 64);
        float b3 = __shfl(al, g*4 + 3, 64);
        #pragma unroll
        for (int nd = 0; nd < 4; nd++){
          oacc[nd][0] *= b0; oacc[nd][1] *= b1;
          oacc[nd][2] *= b2; oacc[nd][3] *= b3;
        }
      }

      // P = exp2((s-m)*log2e): RTNE for PV, tree-sum unrounded into per-lane l
      short8 pa[2];
      {
        const float nm = -mrun * LOG2E;
        float p[16]; u32 rb[16];
        #pragma unroll
        for (int nt = 0; nt < 4; nt++)
          #pragma unroll
          for (int r = 0; r < 4; r++){
            float pp = exp2f(fmaf(sacc[nt][r], LOG2E, nm));
            p[nt*4 + r] = pp;
            u32 u = __builtin_bit_cast(u32, pp);
            rb[nt*4 + r] = u + 0x7FFFu + ((u >> 16) & 1u);   // RTNE in bytes 2,3
          }
        float s0 = (p[0] + p[1]) + (p[2] + p[3]);
        float s1 = (p[4] + p[5]) + (p[6] + p[7]);
        float s2 = (p[8] + p[9]) + (p[10] + p[11]);
        float s3 = (p[12] + p[13]) + (p[14] + p[15]);
        lrun += (s0 + s1) + (s2 + s3);
        u32x4 q0 = { __builtin_amdgcn_perm(rb[1],  rb[0],  0x07060302u),
                     __builtin_amdgcn_perm(rb[3],  rb[2],  0x07060302u),
                     __builtin_amdgcn_perm(rb[5],  rb[4],  0x07060302u),
                     __builtin_amdgcn_perm(rb[7],  rb[6],  0x07060302u) };
        u32x4 q1 = { __builtin_amdgcn_perm(rb[9],  rb[8],  0x07060302u),
                     __builtin_amdgcn_perm(rb[11], rb[10], 0x07060302u),
                     __builtin_amdgcn_perm(rb[13], rb[12], 0x07060302u),
                     __builtin_amdgcn_perm(rb[15], rb[14], 0x07060302u) };
        pa[0] = __builtin_bit_cast(short8, q0);
        pa[1] = __builtin_bit_cast(short8, q1);
      }

      // O += P (A) x V (B): V row = nd*16+c, t-chunk = (half*8+ki*4+g)^c
      #pragma unroll
      for (int ki = 0; ki < 2; ki++){
        short8 va[4];
        #pragma unroll
        for (int nd = 0; nd < 4; nd++)
          va[nd] = *(const short8*)&Vb[(nd*16 + c)*128 + (((half*8 + ki*4 + g) ^ c) * 8)];
        #pragma unroll
        for (int nd = 0; nd < 4; nd++)
          oacc[nd] = mfma16(pa[ki], va[nd], oacc[nd]);
      }
    }

    asm volatile("" ::: "memory");
    __builtin_amdgcn_s_barrier();
    asm volatile("" ::: "memory");
  }

  // epilogue: reduce per-lane l partials once; O rows q = qw + 4g + r
  lrun += __shfl_xor(lrun, 16, 64);
  lrun += __shfl_xor(lrun, 32, 64);
  #pragma unroll
  for (int r = 0; r < 4; r++){
    float li = __shfl(lrun, g*4 + r, 64);
    float inv = 1.0f / li;
    int q = qw + g*4 + r;
    size_t base = ((size_t)b*2048 + q)*1024 + h*64;
    #pragma unroll
    for (int nd = 0; nd < 4; nd++)
      AO[base + nd*16 + c] = f2bf(oacc[nd][r] * inv);
  }
}

extern "C" void kernel_launch(void* const* d_in, const int* in_sizes, int n_in,
                              void* d_out, int out_size, void* d_ws, size_t ws_size,
                              hipStream_t stream)
{
  const float* x  = (const float*)d_in[0];
  const int* mask = (const int*)d_in[1];
  const float* Wq = (const float*)d_in[2];
  const float* bq = (const float*)d_in[3];
  const float* Wk = (const float*)d_in[4];
  const float* bk = (const float*)d_in[5];
  const float* Wv = (const float*)d_in[6];
  const float* bv = (const float*)d_in[7];
  const float* Wo = (const float*)d_in[8];
  const float* bo = (const float*)d_in[9];
  float* out = (float*)d_out;
  (void)in_sizes; (void)n_in; (void)out_size; (void)ws_size;

  char* ws = (char*)d_ws;
  size_t off = 0;
  auto alloc = [&](size_t bytes){ void* p = ws + off; off += (bytes + 255) & ~(size_t)255; return p; };
  u16* xb    = (u16*)alloc((size_t)8192 * 1024 * 2);
  u16* WT    = (u16*)alloc((size_t)4 * 1024 * 1024 * 2);
  float* cosT = (float*)alloc((size_t)2048 * 32 * 4);
  float* sinT = (float*)alloc((size_t)2048 * 32 * 4);
  u16* Qr    = (u16*)alloc((size_t)8192 * 1024 * 2);
  u16* Kr    = (u16*)alloc((size_t)8192 * 1024 * 2);
  u16* Vt    = (u16*)alloc((size_t)8192 * 1024 * 2);
  u16* AO    = (u16*)alloc((size_t)8192 * 1024 * 2);

  rope_tab_k<<<dim3(256), dim3(256), 0, stream>>>(cosT, sinT);
  cvt_x_k<<<dim3(8192), dim3(256), 0, stream>>>(x, xb, 8192 * 1024);
  wt_cvt_k<<<dim3(32, 32, 4), dim3(32, 8), 0, stream>>>(Wq, Wk, Wv, Wo, WT);

  qkv_gemm_k<<<dim3(64, 24), dim3(256), 0, stream>>>(xb, WT, bq, bk, bv, cosT, sinT, Qr, Kr, Vt);

  attn_fwd_k<<<dim3(16, 64), dim3(512), 0, stream>>>(Qr, Kr, Vt, mask, AO);

  out_gemm_k<<<dim3(64, 8), dim3(256), 0, stream>>>(AO, WT + 3*1024*1024, bo, out);
}

// Round 12
// 344.977 us; speedup vs baseline: 1.0425x; 1.0425x over previous
//
#include <hip/hip_runtime.h>
#include <math.h>

typedef __attribute__((ext_vector_type(8))) short short8;
typedef __attribute__((ext_vector_type(4))) float f32x4;
typedef __attribute__((ext_vector_type(4))) unsigned short us4;
typedef __attribute__((ext_vector_type(4))) unsigned int u32x4;
typedef __attribute__((ext_vector_type(4))) int i32x4;
typedef unsigned short u16;
typedef unsigned int u32;

#define LOG2E 1.4426950408889634f
// B=4, S=2048, E=1024, H=16, D=64, M=B*S=8192

static __device__ __forceinline__ u16 f2bf(float f){
  u32 u = __builtin_bit_cast(u32, f);
  u = (u + 0x7FFFu + ((u >> 16) & 1u)) >> 16;   // RTNE
  return (u16)u;
}
// NOTE: v_cvt_pk_bf16_f32 (and __float22bfloat162_rn) is NOT RTNE on gfx950 —
// using it for the P-pack cost 7e-3 absmax (rounds 2 & 5). Keep manual RTNE.
// NOTE2: 2-tile software pipeline (round 8) regressed 173->307us: VGPR spill
// (scratch WRITE 333MB) + lost block co-residency (FETCH 34->189MB). Use TLP.
// NOTE3: K direct-from-global (round 11) regressed 152->274us: un-prefetched
// L2 loads between barrier and MFMA expose full latency (MfmaUtil halved).

static __device__ __forceinline__ void gload16(const void* g, void* l){
  __builtin_amdgcn_global_load_lds((const __attribute__((address_space(1))) void*)g,
                                   (__attribute__((address_space(3))) void*)l,
                                   16, 0, 0);
}

static __device__ __forceinline__ f32x4 mfma16(short8 a, short8 b, f32x4 c){
  return __builtin_amdgcn_mfma_f32_16x16x32_bf16(a, b, c, 0, 0, 0);
}

// ---------------- RoPE cos/sin table: [s][i], i = 0..31 ----------------
__global__ void rope_tab_k(float* __restrict__ cosT, float* __restrict__ sinT){
  int idx = blockIdx.x * 256 + threadIdx.x;   // 2048*32 = 65536
  int s = idx >> 5, i = idx & 31;
  double th = pow(10000.0, -((double)(2 * i)) / 64.0);
  float ang = (float)s * (float)th;           // fp32 rounding matches reference
  cosT[idx] = (float)cos((double)ang);
  sinT[idx] = (float)sin((double)ang);
}

// ---------------- x fp32 -> bf16 ----------------
__global__ void cvt_x_k(const float* __restrict__ x, u16* __restrict__ xb, int n){
  int i = (blockIdx.x * 256 + threadIdx.x) * 4;
  if (i >= n) return;
  f32x4 v = *(const f32x4*)(x + i);
  us4 o; o[0]=f2bf(v[0]); o[1]=f2bf(v[1]); o[2]=f2bf(v[2]); o[3]=f2bf(v[3]);
  *(us4*)(xb + i) = o;
}

// ---------------- W (k,n) fp32 -> WT (n,k) bf16, 4 matrices ----------------
__global__ void wt_cvt_k(const float* __restrict__ W0, const float* __restrict__ W1,
                         const float* __restrict__ W2, const float* __restrict__ W3,
                         u16* __restrict__ out){
  __shared__ float t[32][33];
  const float* W = (blockIdx.z == 0) ? W0 : (blockIdx.z == 1) ? W1 : (blockIdx.z == 2) ? W2 : W3;
  u16* O = out + (size_t)blockIdx.z * 1024 * 1024;
  int tx = threadIdx.x, ty = threadIdx.y;
  int kb = blockIdx.y * 32, nb = blockIdx.x * 32;
  #pragma unroll
  for (int i = 0; i < 4; i++)
    t[ty + i*8][tx] = W[(size_t)(kb + ty + i*8) * 1024 + nb + tx];
  __syncthreads();
  #pragma unroll
  for (int i = 0; i < 4; i++)
    O[(size_t)(nb + ty + i*8) * 1024 + kb + tx] = f2bf(t[tx][ty + i*8]);
}

// ---------------- fused QKV GEMM 8192x1024x1024 bf16 MFMA ----------------
__global__ __launch_bounds__(256, 2)
void qkv_gemm_k(const u16* __restrict__ A, const u16* __restrict__ WT,
                const float* __restrict__ bq, const float* __restrict__ bk,
                const float* __restrict__ bv,
                const float* __restrict__ cosT, const float* __restrict__ sinT,
                u16* __restrict__ Qr, u16* __restrict__ Kr, u16* __restrict__ Vt)
{
  __shared__ __align__(16) u16 Al[128][64];
  __shared__ __align__(16) u16 Bl[128][64];
  const int mode = blockIdx.y >> 3;
  const int cy   = blockIdx.y & 7;
  const u16* BT = WT + (size_t)mode * 1024 * 1024;
  const float* bias = (mode == 0) ? bq : (mode == 1) ? bk : bv;
  u16* outB = (mode == 0) ? Qr : (mode == 1) ? Kr : Vt;

  const int tid = threadIdx.x;
  const int w = tid >> 6, lane = tid & 63, g = lane >> 4, c = lane & 15;
  const int wr = w >> 1, wc = w & 1;
  const int R0 = blockIdx.x * 128, C0 = cy * 128;

  f32x4 acc[4][4];
  const f32x4 vz = {0.f, 0.f, 0.f, 0.f};
  #pragma unroll
  for (int mi = 0; mi < 4; mi++)
    #pragma unroll
    for (int ni = 0; ni < 4; ni++) acc[mi][ni] = vz;

  const u16* gA[4]; const u16* gB[4]; u16* lA[4]; u16* lB[4];
  #pragma unroll
  for (int i = 0; i < 4; i++){
    int I = w * 4 + i;
    int rr = I * 8 + (lane >> 3), kk = (lane & 7) * 8;
    gA[i] = A  + (size_t)(R0 + rr) * 1024 + kk;
    gB[i] = BT + (size_t)(C0 + rr) * 1024 + kk;
    lA[i] = &Al[I * 8][0];
    lB[i] = &Bl[I * 8][0];
  }

  for (int t = 0; t < 16; ++t){
    const int k0 = t * 64;
    #pragma unroll
    for (int i = 0; i < 4; i++){
      gload16(gA[i] + k0, lA[i]);
      gload16(gB[i] + k0, lB[i]);
    }
    __syncthreads();
    #pragma unroll
    for (int ki = 0; ki < 2; ++ki){
      short8 af[4], bfr[4];
      #pragma unroll
      for (int mi = 0; mi < 4; mi++) af[mi]  = *(const short8*)&Al[wr*64 + mi*16 + c][ki*32 + g*8];
      #pragma unroll
      for (int ni = 0; ni < 4; ni++) bfr[ni] = *(const short8*)&Bl[wc*64 + ni*16 + c][ki*32 + g*8];
      #pragma unroll
      for (int mi = 0; mi < 4; mi++)
        #pragma unroll
        for (int ni = 0; ni < 4; ni++)
          acc[mi][ni] = mfma16(af[mi], bfr[ni], acc[mi][ni]);
    }
    __syncthreads();
  }

  if (mode == 2){
    int h = cy * 2 + wc;
    #pragma unroll
    for (int ni = 0; ni < 4; ni++){
      int col = C0 + wc*64 + ni*16 + c;
      int d = ni*16 + c;
      float bvv = bias[col];
      #pragma unroll
      for (int mi = 0; mi < 4; mi++){
        int row0 = R0 + wr*64 + mi*16 + g*4;
        int b = row0 >> 11, s0 = row0 & 2047;
        us4 pk;
        #pragma unroll
        for (int r = 0; r < 4; r++) pk[r] = f2bf(acc[mi][ni][r] + bvv);
        *(us4*)&outB[((size_t)(b*16 + h)*64 + d)*2048 + s0] = pk;
      }
    }
  } else {
    int h = cy * 2 + wc;
    const float qs = (mode == 0) ? 0.125f : 1.0f;
    float bvv[4];
    #pragma unroll
    for (int ni = 0; ni < 4; ni++) bvv[ni] = bias[C0 + wc*64 + ni*16 + c];
    #pragma unroll
    for (int mi = 0; mi < 4; mi++){
      int row0 = R0 + wr*64 + mi*16 + g*4;
      int b = row0 >> 11;
      #pragma unroll
      for (int r = 0; r < 4; r++){
        int s = (row0 + r) & 2047;
        float v0 = acc[mi][0][r] + bvv[0];
        float v1 = acc[mi][1][r] + bvv[1];
        float v2 = acc[mi][2][r] + bvv[2];
        float v3 = acc[mi][3][r] + bvv[3];
        float ca = cosT[s*32 + c],      sa = sinT[s*32 + c];
        float cb = cosT[s*32 + 16 + c], sb = sinT[s*32 + 16 + c];
        float o0 = (v0*ca - v2*sa) * qs, o2 = (v2*ca + v0*sa) * qs;
        float o1 = (v1*cb - v3*sb) * qs, o3 = (v3*cb + v1*sb) * qs;
        size_t base = ((size_t)(b*16 + h)*2048 + s)*64;
        outB[base +  0 + c] = f2bf(o0);
        outB[base + 16 + c] = f2bf(o1);
        outB[base + 32 + c] = f2bf(o2);
        outB[base + 48 + c] = f2bf(o3);
      }
    }
  }
}

// ---------------- output GEMM (AO x Wo^T + bo -> fp32 out) ----------------
__global__ __launch_bounds__(256, 2)
void out_gemm_k(const u16* __restrict__ A, const u16* __restrict__ BT,
                const float* __restrict__ bias, float* __restrict__ outF)
{
  __shared__ __align__(16) u16 Al[128][64];
  __shared__ __align__(16) u16 Bl[128][64];
  const int tid = threadIdx.x;
  const int w = tid >> 6, lane = tid & 63, g = lane >> 4, c = lane & 15;
  const int wr = w >> 1, wc = w & 1;
  const int R0 = blockIdx.x * 128, C0 = blockIdx.y * 128;

  f32x4 acc[4][4];
  const f32x4 vz = {0.f, 0.f, 0.f, 0.f};
  #pragma unroll
  for (int mi = 0; mi < 4; mi++)
    #pragma unroll
    for (int ni = 0; ni < 4; ni++) acc[mi][ni] = vz;

  const u16* gA[4]; const u16* gB[4]; u16* lA[4]; u16* lB[4];
  #pragma unroll
  for (int i = 0; i < 4; i++){
    int I = w * 4 + i;
    int rr = I * 8 + (lane >> 3), kk = (lane & 7) * 8;
    gA[i] = A  + (size_t)(R0 + rr) * 1024 + kk;
    gB[i] = BT + (size_t)(C0 + rr) * 1024 + kk;
    lA[i] = &Al[I * 8][0];
    lB[i] = &Bl[I * 8][0];
  }

  for (int t = 0; t < 16; ++t){
    const int k0 = t * 64;
    #pragma unroll
    for (int i = 0; i < 4; i++){
      gload16(gA[i] + k0, lA[i]);
      gload16(gB[i] + k0, lB[i]);
    }
    __syncthreads();
    #pragma unroll
    for (int ki = 0; ki < 2; ++ki){
      short8 af[4], bfr[4];
      #pragma unroll
      for (int mi = 0; mi < 4; mi++) af[mi]  = *(const short8*)&Al[wr*64 + mi*16 + c][ki*32 + g*8];
      #pragma unroll
      for (int ni = 0; ni < 4; ni++) bfr[ni] = *(const short8*)&Bl[wc*64 + ni*16 + c][ki*32 + g*8];
      #pragma unroll
      for (int mi = 0; mi < 4; mi++)
        #pragma unroll
        for (int ni = 0; ni < 4; ni++)
          acc[mi][ni] = mfma16(af[mi], bfr[ni], acc[mi][ni]);
    }
    __syncthreads();
  }

  #pragma unroll
  for (int mi = 0; mi < 4; mi++){
    #pragma unroll
    for (int ni = 0; ni < 4; ni++){
      int col = C0 + wc*64 + ni*16 + c;
      float bvv = bias[col];
      int row0 = R0 + wr*64 + mi*16 + g*4;
      #pragma unroll
      for (int r = 0; r < 4; r++)
        outF[(size_t)(row0 + r) * 1024 + col] = acc[mi][ni][r] + bvv;
    }
  }
}

// ---------------- flash attention (8 waves x 32 q-rows, KVBLK=128) ----------------
// Q,K: (b,h,s,d) bf16 (Q pre-scaled by 0.125).  V: (b,h,d,s) bf16.
// out AO: (b,s,h,d) bf16.  512 threads = 8 waves, 32 q-rows each (256/block).
// 2x FLOPs per LDS byte vs 16-q/wave (K/V tile reads shared across mq=2).
// Grid (8,64) = 512 blocks = ONE co-resident pass (2 blocks/CU).
// KV tiles of 128 rows, double-buffered, processed as two sequential 64-halves.
// K LDS: [2][128][64], 8-chunk XOR swizzle.  V LDS: [2][64][128], 16-chunk XOR.
__global__ __launch_bounds__(512, 4)
void attn_fwd_k(const u16* __restrict__ Q, const u16* __restrict__ K, const u16* __restrict__ V,
                const int* __restrict__ msk, u16* __restrict__ AO)
{
  __shared__ __align__(16) u16 Kl[2][128][64];
  __shared__ __align__(16) u16 Vl[2][64][128];
  __shared__ __align__(8) unsigned char Ml[2048];
  const int tid = threadIdx.x;
  const int w = tid >> 6, lane = tid & 63, g = lane >> 4, c = lane & 15;

  // XCD-aware swizzle (bijective, 512 = 8*64): XCD = lin%8 gets 8 full bh
  const int lin = blockIdx.y * 8 + blockIdx.x;
  const int v_  = (lin & 7) * 64 + (lin >> 3);
  const int bh = v_ >> 3, b = bh >> 4, h = bh & 15;
  const int qw = (v_ & 7) * 256 + w * 32;

  // Q B-fragments FIRST (4 global loads; drained by first vmcnt(4))
  short8 qb[2][2];
  #pragma unroll
  for (int mq = 0; mq < 2; mq++)
    #pragma unroll
    for (int ki = 0; ki < 2; ki++)
      qb[mq][ki] = *(const short8*)&Q[((size_t)bh*2048 + qw + mq*16 + c)*64 + ki*32 + g*8];

  // K staging: 2 loads/wave, stored rows sr = w*16 + j*8 + l3 (pi within 64-half)
  const int l3 = lane >> 3, l7 = lane & 7;
  const int kcol = (l7 ^ l3) * 8;                 // pre-swizzled d-chunk (8 chunks/row)
  const u16* gKs[2];
  #pragma unroll
  for (int j = 0; j < 2; j++){
    int sr = w*16 + j*8 + l3;
    int s = sr & 63;
    int ps = (s & 0x20) | ((s & 0x10) >> 2) | ((s & 0x0C) << 1) | (s & 3);  // pi(s)
    gKs[j] = K + ((size_t)bh*2048 + (sr & 64) + ps)*64 + kcol;
  }
  // V staging: 2 loads/wave, rows vr = w*8 + j*4 + (lane>>4), 16-chunk XOR swizzle
  const u16* gVs[2];
  #pragma unroll
  for (int j = 0; j < 2; j++){
    int vr = w*8 + j*4 + (lane >> 4);
    int lc = (lane & 15) ^ (vr & 15);            // logical t-chunk for this physical slot
    gVs[j] = V + ((size_t)bh*64 + vr)*2048 + lc*8;
  }

  // stage tile 0 into buf 0
  #pragma unroll
  for (int j = 0; j < 2; j++) gload16(gKs[j], &Kl[0][w*16 + j*8][0]);
  #pragma unroll
  for (int j = 0; j < 2; j++) gload16(gVs[j], &Vl[0][w*8 + j*4][0]);

  // pack mask row for this b into LDS as u8 (0/1): 512 thr x 4 ints
  {
    const int* mp = msk + b*2048 + tid*4;
    i32x4 a = *(const i32x4*)mp;
    u32 lo = (a[0] ? 1u : 0u) | (a[1] ? 0x100u : 0u) | (a[2] ? 0x10000u : 0u) | (a[3] ? 0x1000000u : 0u);
    *(u32*)&Ml[tid*4] = lo;
  }
  asm volatile("s_waitcnt lgkmcnt(0)" ::: "memory");  // Ml writes drained before first barrier

  f32x4 oacc[2][4];
  float mrun[2], lrun[2];
  const f32x4 vz = {0.f, 0.f, 0.f, 0.f};
  #pragma unroll
  for (int mq = 0; mq < 2; mq++){
    #pragma unroll
    for (int nd = 0; nd < 4; nd++) oacc[mq][nd] = vz;
    mrun[mq] = -1e30f; lrun[mq] = 0.f;
  }

  for (int t = 0; t < 16; ++t){
    // stage tile t+1 into buf (t+1)&1  (t=15 over-stage is harmless, in-ws)
    {
      const size_t ko = (size_t)(t+1) * 128 * 64;   // u16: 128 rows ahead
      const size_t vo = (size_t)(t+1) * 128;        // u16: 128 t's ahead
      #pragma unroll
      for (int j = 0; j < 2; j++) gload16(gKs[j] + ko, &Kl[(t+1)&1][w*16 + j*8][0]);
      #pragma unroll
      for (int j = 0; j < 2; j++) gload16(gVs[j] + vo, &Vl[(t+1)&1][w*8 + j*4][0]);
    }
    asm volatile("s_waitcnt vmcnt(4)" ::: "memory");  // tile t drained; t+1 in flight
    __builtin_amdgcn_s_barrier();
    asm volatile("" ::: "memory");

    const u16* Kb = &Kl[t&1][0][0];
    const u16* Vb = &Vl[t&1][0][0];

    #pragma unroll
    for (int half = 0; half < 2; ++half){
      const int t0 = t * 128 + half * 64;

      // S^T = K (A) x Q (B): sacc[nt][mq] = S[q=qw+mq*16+c][t0+nt*16+4g+r]
      f32x4 sacc[4][2];
      #pragma unroll
      for (int nt = 0; nt < 4; nt++){ sacc[nt][0] = vz; sacc[nt][1] = vz; }
      #pragma unroll
      for (int ki = 0; ki < 2; ki++){
        const int cs = (((ki*4 + g) ^ (c & 7)) * 8);
        short8 ka[4];
        #pragma unroll
        for (int nt = 0; nt < 4; nt++)
          ka[nt] = *(const short8*)&Kb[(half*64 + nt*16 + c)*64 + cs];
        #pragma unroll
        for (int nt = 0; nt < 4; nt++)
          #pragma unroll
          for (int mq = 0; mq < 2; mq++)
            sacc[nt][mq] = mfma16(ka[nt], qb[mq][ki], sacc[nt][mq]);
      }

      // mask (u8): logical t of (nt,g,r) = t0 + 32*(nt>>1) + 8g + 4*(nt&1) + r
      {
        const u32 mw0 = *(const u32*)&Ml[t0 + 8*g];
        const u32 mw1 = *(const u32*)&Ml[t0 + 8*g + 4];
        const u32 mw2 = *(const u32*)&Ml[t0 + 32 + 8*g];
        const u32 mw3 = *(const u32*)&Ml[t0 + 32 + 8*g + 4];
        if (!__all((mw0 & mw1 & mw2 & mw3) == 0x01010101u)){
          const u32 mw[4] = {mw0, mw1, mw2, mw3};
          #pragma unroll
          for (int nt = 0; nt < 4; nt++)
            #pragma unroll
            for (int r = 0; r < 4; r++)
              if (((mw[nt] >> (8*r)) & 0xFFu) == 0){ sacc[nt][0][r] = -1e9f; sacc[nt][1][r] = -1e9f; }
        }
      }

      // tile max (tree) per mq, row q = qw + mq*16 + c
      float pm[2];
      #pragma unroll
      for (int mq = 0; mq < 2; mq++){
        float a0 = fmaxf(fmaxf(sacc[0][mq][0], sacc[0][mq][1]), fmaxf(sacc[0][mq][2], sacc[0][mq][3]));
        float a1 = fmaxf(fmaxf(sacc[1][mq][0], sacc[1][mq][1]), fmaxf(sacc[1][mq][2], sacc[1][mq][3]));
        float a2 = fmaxf(fmaxf(sacc[2][mq][0], sacc[2][mq][1]), fmaxf(sacc[2][mq][2], sacc[2][mq][3]));
        float a3 = fmaxf(fmaxf(sacc[3][mq][0], sacc[3][mq][1]), fmaxf(sacc[3][mq][2], sacc[3][mq][3]));
        float mm = fmaxf(fmaxf(a0, a1), fmaxf(a2, a3));
        mm = fmaxf(mm, __shfl_xor(mm, 16, 64));
        mm = fmaxf(mm, __shfl_xor(mm, 32, 64));
        pm[mq] = mm;
      }

      // defer-max: rescale only when max grew by > 8 (skip is EXACT when pm<=mrun)
      if (__any((pm[0] > mrun[0] + 8.f) | (pm[1] > mrun[1] + 8.f))){
        float al[2];
        #pragma unroll
        for (int mq = 0; mq < 2; mq++){
          float mn = fmaxf(mrun[mq], pm[mq]);
          al[mq] = exp2f((mrun[mq] - mn) * LOG2E);
          mrun[mq] = mn;
          lrun[mq] *= al[mq];                   // per-lane partial, al row-uniform
        }
        #pragma unroll
        for (int mq = 0; mq < 2; mq++){
          float b0 = __shfl(al[mq], g*4 + 0, 64);
          float b1 = __shfl(al[mq], g*4 + 1, 64);
          float b2 = __shfl(al[mq], g*4 + 2, 64);
          float b3 = __shfl(al[mq], g*4 + 3, 64);
          #pragma unroll
          for (int nd = 0; nd < 4; nd++){
            oacc[mq][nd][0] *= b0; oacc[mq][nd][1] *= b1;
            oacc[mq][nd][2] *= b2; oacc[mq][nd][3] *= b3;
          }
        }
      }

      // P = exp2((s-m)*log2e): RTNE for PV, tree-sum unrounded into per-lane l
      short8 pa[2][2];
      #pragma unroll
      for (int mq = 0; mq < 2; mq++){
        const float nm = -mrun[mq] * LOG2E;
        float p[16]; u32 rb[16];
        #pragma unroll
        for (int nt = 0; nt < 4; nt++)
          #pragma unroll
          for (int r = 0; r < 4; r++){
            float pp = exp2f(fmaf(sacc[nt][mq][r], LOG2E, nm));
            p[nt*4 + r] = pp;
            u32 u = __builtin_bit_cast(u32, pp);
            rb[nt*4 + r] = u + 0x7FFFu + ((u >> 16) & 1u);   // RTNE in bytes 2,3
          }
        float s0 = (p[0] + p[1]) + (p[2] + p[3]);
        float s1 = (p[4] + p[5]) + (p[6] + p[7]);
        float s2 = (p[8] + p[9]) + (p[10] + p[11]);
        float s3 = (p[12] + p[13]) + (p[14] + p[15]);
        lrun[mq] += (s0 + s1) + (s2 + s3);
        u32x4 q0 = { __builtin_amdgcn_perm(rb[1],  rb[0],  0x07060302u),
                     __builtin_amdgcn_perm(rb[3],  rb[2],  0x07060302u),
                     __builtin_amdgcn_perm(rb[5],  rb[4],  0x07060302u),
                     __builtin_amdgcn_perm(rb[7],  rb[6],  0x07060302u) };
        u32x4 q1 = { __builtin_amdgcn_perm(rb[9],  rb[8],  0x07060302u),
                     __builtin_amdgcn_perm(rb[11], rb[10], 0x07060302u),
                     __builtin_amdgcn_perm(rb[13], rb[12], 0x07060302u),
                     __builtin_amdgcn_perm(rb[15], rb[14], 0x07060302u) };
        pa[mq][0] = __builtin_bit_cast(short8, q0);
        pa[mq][1] = __builtin_bit_cast(short8, q1);
      }

      // O += P (A) x V (B): V row = nd*16+c, t-chunk = (half*8+ki*4+g)^c
      #pragma unroll
      for (int ki = 0; ki < 2; ki++){
        short8 va[4];
        #pragma unroll
        for (int nd = 0; nd < 4; nd++)
          va[nd] = *(const short8*)&Vb[(nd*16 + c)*128 + (((half*8 + ki*4 + g) ^ c) * 8)];
        #pragma unroll
        for (int mq = 0; mq < 2; mq++)
          #pragma unroll
          for (int nd = 0; nd < 4; nd++)
            oacc[mq][nd] = mfma16(pa[mq][ki], va[nd], oacc[mq][nd]);
      }
    }

    asm volatile("" ::: "memory");
    __builtin_amdgcn_s_barrier();
    asm volatile("" ::: "memory");
  }

  // epilogue: reduce per-lane l partials once; O rows q = qw + mq*16 + 4g + r
  #pragma unroll
  for (int mq = 0; mq < 2; mq++){
    lrun[mq] += __shfl_xor(lrun[mq], 16, 64);
    lrun[mq] += __shfl_xor(lrun[mq], 32, 64);
    #pragma unroll
    for (int r = 0; r < 4; r++){
      float li = __shfl(lrun[mq], g*4 + r, 64);
      float inv = 1.0f / li;
      int q = qw + mq*16 + g*4 + r;
      size_t base = ((size_t)b*2048 + q)*1024 + h*64;
      #pragma unroll
      for (int nd = 0; nd < 4; nd++)
        AO[base + nd*16 + c] = f2bf(oacc[mq][nd][r] * inv);
    }
  }
}

extern "C" void kernel_launch(void* const* d_in, const int* in_sizes, int n_in,
                              void* d_out, int out_size, void* d_ws, size_t ws_size,
                              hipStream_t stream)
{
  const float* x  = (const float*)d_in[0];
  const int* mask = (const int*)d_in[1];
  const float* Wq = (const float*)d_in[2];
  const float* bq = (const float*)d_in[3];
  const float* Wk = (const float*)d_in[4];
  const float* bk = (const float*)d_in[5];
  const float* Wv = (const float*)d_in[6];
  const float* bv = (const float*)d_in[7];
  const float* Wo = (const float*)d_in[8];
  const float* bo = (const float*)d_in[9];
  float* out = (float*)d_out;
  (void)in_sizes; (void)n_in; (void)out_size; (void)ws_size;

  char* ws = (char*)d_ws;
  size_t off = 0;
  auto alloc = [&](size_t bytes){ void* p = ws + off; off += (bytes + 255) & ~(size_t)255; return p; };
  u16* xb    = (u16*)alloc((size_t)8192 * 1024 * 2);
  u16* WT    = (u16*)alloc((size_t)4 * 1024 * 1024 * 2);
  float* cosT = (float*)alloc((size_t)2048 * 32 * 4);
  float* sinT = (float*)alloc((size_t)2048 * 32 * 4);
  u16* Qr    = (u16*)alloc((size_t)8192 * 1024 * 2);
  u16* Kr    = (u16*)alloc((size_t)8192 * 1024 * 2);
  u16* Vt    = (u16*)alloc((size_t)8192 * 1024 * 2);
  u16* AO    = (u16*)alloc((size_t)8192 * 1024 * 2);

  rope_tab_k<<<dim3(256), dim3(256), 0, stream>>>(cosT, sinT);
  cvt_x_k<<<dim3(8192), dim3(256), 0, stream>>>(x, xb, 8192 * 1024);
  wt_cvt_k<<<dim3(32, 32, 4), dim3(32, 8), 0, stream>>>(Wq, Wk, Wv, Wo, WT);

  qkv_gemm_k<<<dim3(64, 24), dim3(256), 0, stream>>>(xb, WT, bq, bk, bv, cosT, sinT, Qr, Kr, Vt);

  attn_fwd_k<<<dim3(8, 64), dim3(512), 0, stream>>>(Qr, Kr, Vt, mask, AO);

  out_gemm_k<<<dim3(64, 8), dim3(256), 0, stream>>>(AO, WT + 3*1024*1024, bo, out);
}

// Round 13
// 242.679 us; speedup vs baseline: 1.4820x; 1.4215x over previous
//
#include <hip/hip_runtime.h>
#include <math.h>

typedef __attribute__((ext_vector_type(8))) short short8;
typedef __attribute__((ext_vector_type(4))) float f32x4;
typedef __attribute__((ext_vector_type(4))) unsigned short us4;
typedef __attribute__((ext_vector_type(4))) unsigned int u32x4;
typedef __attribute__((ext_vector_type(4))) int i32x4;
typedef unsigned short u16;
typedef unsigned int u32;

#define LOG2E 1.4426950408889634f
// B=4, S=2048, E=1024, H=16, D=64, M=B*S=8192

static __device__ __forceinline__ u16 f2bf(float f){
  u32 u = __builtin_bit_cast(u32, f);
  u = (u + 0x7FFFu + ((u >> 16) & 1u)) >> 16;   // RTNE
  return (u16)u;
}
// NOTE: v_cvt_pk_bf16_f32 (and __float22bfloat162_rn) is NOT RTNE on gfx950 —
// using it for the P-pack cost 7e-3 absmax (rounds 2 & 5). Keep manual RTNE.
// NOTE2: 2-tile software pipeline (round 8) regressed 173->307us: VGPR spill
// (scratch WRITE 333MB) + lost block co-residency (FETCH 34->189MB). Use TLP.
// NOTE3: K direct-from-global (round 11) regressed 152->274us: un-prefetched
// L2 loads between barrier and MFMA expose full latency (MfmaUtil halved).
// NOTE4: mq=2 + KVBLK=128 half-unroll (round 12) spilled (FETCH/WRITE ~460MB).
// mq=2 fits registers only in the r7 body form: KVBLK=64, no half-unroll.

static __device__ __forceinline__ void gload16(const void* g, void* l){
  __builtin_amdgcn_global_load_lds((const __attribute__((address_space(1))) void*)g,
                                   (__attribute__((address_space(3))) void*)l,
                                   16, 0, 0);
}

static __device__ __forceinline__ f32x4 mfma16(short8 a, short8 b, f32x4 c){
  return __builtin_amdgcn_mfma_f32_16x16x32_bf16(a, b, c, 0, 0, 0);
}

// ---------------- RoPE cos/sin table: [s][i], i = 0..31 ----------------
__global__ void rope_tab_k(float* __restrict__ cosT, float* __restrict__ sinT){
  int idx = blockIdx.x * 256 + threadIdx.x;   // 2048*32 = 65536
  int s = idx >> 5, i = idx & 31;
  double th = pow(10000.0, -((double)(2 * i)) / 64.0);
  float ang = (float)s * (float)th;           // fp32 rounding matches reference
  cosT[idx] = (float)cos((double)ang);
  sinT[idx] = (float)sin((double)ang);
}

// ---------------- x fp32 -> bf16 ----------------
__global__ void cvt_x_k(const float* __restrict__ x, u16* __restrict__ xb, int n){
  int i = (blockIdx.x * 256 + threadIdx.x) * 4;
  if (i >= n) return;
  f32x4 v = *(const f32x4*)(x + i);
  us4 o; o[0]=f2bf(v[0]); o[1]=f2bf(v[1]); o[2]=f2bf(v[2]); o[3]=f2bf(v[3]);
  *(us4*)(xb + i) = o;
}

// ---------------- W (k,n) fp32 -> WT (n,k) bf16, 4 matrices ----------------
__global__ void wt_cvt_k(const float* __restrict__ W0, const float* __restrict__ W1,
                         const float* __restrict__ W2, const float* __restrict__ W3,
                         u16* __restrict__ out){
  __shared__ float t[32][33];
  const float* W = (blockIdx.z == 0) ? W0 : (blockIdx.z == 1) ? W1 : (blockIdx.z == 2) ? W2 : W3;
  u16* O = out + (size_t)blockIdx.z * 1024 * 1024;
  int tx = threadIdx.x, ty = threadIdx.y;
  int kb = blockIdx.y * 32, nb = blockIdx.x * 32;
  #pragma unroll
  for (int i = 0; i < 4; i++)
    t[ty + i*8][tx] = W[(size_t)(kb + ty + i*8) * 1024 + nb + tx];
  __syncthreads();
  #pragma unroll
  for (int i = 0; i < 4; i++)
    O[(size_t)(nb + ty + i*8) * 1024 + kb + tx] = f2bf(t[tx][ty + i*8]);
}

// ---------------- fused QKV GEMM 8192x1024x1024 bf16 MFMA ----------------
__global__ __launch_bounds__(256, 2)
void qkv_gemm_k(const u16* __restrict__ A, const u16* __restrict__ WT,
                const float* __restrict__ bq, const float* __restrict__ bk,
                const float* __restrict__ bv,
                const float* __restrict__ cosT, const float* __restrict__ sinT,
                u16* __restrict__ Qr, u16* __restrict__ Kr, u16* __restrict__ Vt)
{
  __shared__ __align__(16) u16 Al[128][64];
  __shared__ __align__(16) u16 Bl[128][64];
  const int mode = blockIdx.y >> 3;
  const int cy   = blockIdx.y & 7;
  const u16* BT = WT + (size_t)mode * 1024 * 1024;
  const float* bias = (mode == 0) ? bq : (mode == 1) ? bk : bv;
  u16* outB = (mode == 0) ? Qr : (mode == 1) ? Kr : Vt;

  const int tid = threadIdx.x;
  const int w = tid >> 6, lane = tid & 63, g = lane >> 4, c = lane & 15;
  const int wr = w >> 1, wc = w & 1;
  const int R0 = blockIdx.x * 128, C0 = cy * 128;

  f32x4 acc[4][4];
  const f32x4 vz = {0.f, 0.f, 0.f, 0.f};
  #pragma unroll
  for (int mi = 0; mi < 4; mi++)
    #pragma unroll
    for (int ni = 0; ni < 4; ni++) acc[mi][ni] = vz;

  const u16* gA[4]; const u16* gB[4]; u16* lA[4]; u16* lB[4];
  #pragma unroll
  for (int i = 0; i < 4; i++){
    int I = w * 4 + i;
    int rr = I * 8 + (lane >> 3), kk = (lane & 7) * 8;
    gA[i] = A  + (size_t)(R0 + rr) * 1024 + kk;
    gB[i] = BT + (size_t)(C0 + rr) * 1024 + kk;
    lA[i] = &Al[I * 8][0];
    lB[i] = &Bl[I * 8][0];
  }

  for (int t = 0; t < 16; ++t){
    const int k0 = t * 64;
    #pragma unroll
    for (int i = 0; i < 4; i++){
      gload16(gA[i] + k0, lA[i]);
      gload16(gB[i] + k0, lB[i]);
    }
    __syncthreads();
    #pragma unroll
    for (int ki = 0; ki < 2; ++ki){
      short8 af[4], bfr[4];
      #pragma unroll
      for (int mi = 0; mi < 4; mi++) af[mi]  = *(const short8*)&Al[wr*64 + mi*16 + c][ki*32 + g*8];
      #pragma unroll
      for (int ni = 0; ni < 4; ni++) bfr[ni] = *(const short8*)&Bl[wc*64 + ni*16 + c][ki*32 + g*8];
      #pragma unroll
      for (int mi = 0; mi < 4; mi++)
        #pragma unroll
        for (int ni = 0; ni < 4; ni++)
          acc[mi][ni] = mfma16(af[mi], bfr[ni], acc[mi][ni]);
    }
    __syncthreads();
  }

  if (mode == 2){
    int h = cy * 2 + wc;
    #pragma unroll
    for (int ni = 0; ni < 4; ni++){
      int col = C0 + wc*64 + ni*16 + c;
      int d = ni*16 + c;
      float bvv = bias[col];
      #pragma unroll
      for (int mi = 0; mi < 4; mi++){
        int row0 = R0 + wr*64 + mi*16 + g*4;
        int b = row0 >> 11, s0 = row0 & 2047;
        us4 pk;
        #pragma unroll
        for (int r = 0; r < 4; r++) pk[r] = f2bf(acc[mi][ni][r] + bvv);
        *(us4*)&outB[((size_t)(b*16 + h)*64 + d)*2048 + s0] = pk;
      }
    }
  } else {
    int h = cy * 2 + wc;
    const float qs = (mode == 0) ? 0.125f : 1.0f;
    float bvv[4];
    #pragma unroll
    for (int ni = 0; ni < 4; ni++) bvv[ni] = bias[C0 + wc*64 + ni*16 + c];
    #pragma unroll
    for (int mi = 0; mi < 4; mi++){
      int row0 = R0 + wr*64 + mi*16 + g*4;
      int b = row0 >> 11;
      #pragma unroll
      for (int r = 0; r < 4; r++){
        int s = (row0 + r) & 2047;
        float v0 = acc[mi][0][r] + bvv[0];
        float v1 = acc[mi][1][r] + bvv[1];
        float v2 = acc[mi][2][r] + bvv[2];
        float v3 = acc[mi][3][r] + bvv[3];
        float ca = cosT[s*32 + c],      sa = sinT[s*32 + c];
        float cb = cosT[s*32 + 16 + c], sb = sinT[s*32 + 16 + c];
        float o0 = (v0*ca - v2*sa) * qs, o2 = (v2*ca + v0*sa) * qs;
        float o1 = (v1*cb - v3*sb) * qs, o3 = (v3*cb + v1*sb) * qs;
        size_t base = ((size_t)(b*16 + h)*2048 + s)*64;
        outB[base +  0 + c] = f2bf(o0);
        outB[base + 16 + c] = f2bf(o1);
        outB[base + 32 + c] = f2bf(o2);
        outB[base + 48 + c] = f2bf(o3);
      }
    }
  }
}

// ---------------- output GEMM (AO x Wo^T + bo -> fp32 out) ----------------
__global__ __launch_bounds__(256, 2)
void out_gemm_k(const u16* __restrict__ A, const u16* __restrict__ BT,
                const float* __restrict__ bias, float* __restrict__ outF)
{
  __shared__ __align__(16) u16 Al[128][64];
  __shared__ __align__(16) u16 Bl[128][64];
  const int tid = threadIdx.x;
  const int w = tid >> 6, lane = tid & 63, g = lane >> 4, c = lane & 15;
  const int wr = w >> 1, wc = w & 1;
  const int R0 = blockIdx.x * 128, C0 = blockIdx.y * 128;

  f32x4 acc[4][4];
  const f32x4 vz = {0.f, 0.f, 0.f, 0.f};
  #pragma unroll
  for (int mi = 0; mi < 4; mi++)
    #pragma unroll
    for (int ni = 0; ni < 4; ni++) acc[mi][ni] = vz;

  const u16* gA[4]; const u16* gB[4]; u16* lA[4]; u16* lB[4];
  #pragma unroll
  for (int i = 0; i < 4; i++){
    int I = w * 4 + i;
    int rr = I * 8 + (lane >> 3), kk = (lane & 7) * 8;
    gA[i] = A  + (size_t)(R0 + rr) * 1024 + kk;
    gB[i] = BT + (size_t)(C0 + rr) * 1024 + kk;
    lA[i] = &Al[I * 8][0];
    lB[i] = &Bl[I * 8][0];
  }

  for (int t = 0; t < 16; ++t){
    const int k0 = t * 64;
    #pragma unroll
    for (int i = 0; i < 4; i++){
      gload16(gA[i] + k0, lA[i]);
      gload16(gB[i] + k0, lB[i]);
    }
    __syncthreads();
    #pragma unroll
    for (int ki = 0; ki < 2; ++ki){
      short8 af[4], bfr[4];
      #pragma unroll
      for (int mi = 0; mi < 4; mi++) af[mi]  = *(const short8*)&Al[wr*64 + mi*16 + c][ki*32 + g*8];
      #pragma unroll
      for (int ni = 0; ni < 4; ni++) bfr[ni] = *(const short8*)&Bl[wc*64 + ni*16 + c][ki*32 + g*8];
      #pragma unroll
      for (int mi = 0; mi < 4; mi++)
        #pragma unroll
        for (int ni = 0; ni < 4; ni++)
          acc[mi][ni] = mfma16(af[mi], bfr[ni], acc[mi][ni]);
    }
    __syncthreads();
  }

  #pragma unroll
  for (int mi = 0; mi < 4; mi++){
    #pragma unroll
    for (int ni = 0; ni < 4; ni++){
      int col = C0 + wc*64 + ni*16 + c;
      float bvv = bias[col];
      int row0 = R0 + wr*64 + mi*16 + g*4;
      #pragma unroll
      for (int r = 0; r < 4; r++)
        outF[(size_t)(row0 + r) * 1024 + col] = acc[mi][ni][r] + bvv;
    }
  }
}

// ---------------- flash attention (8 waves x 32 q-rows, KVBLK=64) ----------------
// Q,K: (b,h,s,d) bf16 (Q pre-scaled by 0.125).  V: (b,h,d,s) bf16.
// out AO: (b,s,h,d) bf16.  512 threads = 8 waves, 32 q-rows each (256/block).
// r7's proven mq=2 body (fits 64 VGPR, no spill) at r9's 8-wave TLP.
// KV tiles of 64 rows, double-buffered; 1 K + 1 V staging load per wave -> vmcnt(2).
// Grid (8,64) = 512 blocks = 2/CU fully co-resident; LDS 34KB.
__global__ __launch_bounds__(512, 4)
void attn_fwd_k(const u16* __restrict__ Q, const u16* __restrict__ K, const u16* __restrict__ V,
                const int* __restrict__ msk, u16* __restrict__ AO)
{
  __shared__ __align__(16) u16 Kl[2][64][64];
  __shared__ __align__(16) u16 Vl[2][64][64];
  __shared__ __align__(8) unsigned char Ml[2048];
  const int tid = threadIdx.x;
  const int w = tid >> 6, lane = tid & 63, g = lane >> 4, c = lane & 15;

  // XCD-aware swizzle (bijective, 512 = 8*64): XCD = lin%8 gets 8 full bh
  const int lin = blockIdx.y * 8 + blockIdx.x;
  const int v_  = (lin & 7) * 64 + (lin >> 3);
  const int bh = v_ >> 3, b = bh >> 4, h = bh & 15;
  const int qw = (v_ & 7) * 256 + w * 32;

  // Q B-fragments FIRST (4 global loads)
  short8 qb[2][2];
  #pragma unroll
  for (int mq = 0; mq < 2; mq++)
    #pragma unroll
    for (int ki = 0; ki < 2; ki++)
      qb[mq][ki] = *(const short8*)&Q[((size_t)bh*2048 + qw + mq*16 + c)*64 + ki*32 + g*8];

  // per-lane staging source (pre-swizzled cols; K rows pi-permuted); 1 K + 1 V load/wave
  const int l3 = lane >> 3, l7 = lane & 7;
  const int scol = (l7 ^ l3) * 8;
  const int s8 = w*8 + l3;                                           // stored row
  const int ps = (s8 & 0x20) | ((s8 & 0x10) >> 2) | ((s8 & 0x0C) << 1) | (s8 & 3); // pi
  const u16* gK = K + ((size_t)bh*2048 + ps)*64 + scol;
  const u16* gV = V + ((size_t)bh*64 + s8)*2048 + scol;

  // stage tile 0 into buf 0
  gload16(gK, &Kl[0][w*8][0]);
  gload16(gV, &Vl[0][w*8][0]);

  // pack mask row for this b into LDS as u8 (0/1): 512 thr x 4 ints (1 VMEM load)
  {
    const int* mp = msk + b*2048 + tid*4;
    i32x4 a = *(const i32x4*)mp;
    u32 lo = (a[0] ? 1u : 0u) | (a[1] ? 0x100u : 0u) | (a[2] ? 0x10000u : 0u) | (a[3] ? 0x1000000u : 0u);
    *(u32*)&Ml[tid*4] = lo;
  }
  asm volatile("s_waitcnt lgkmcnt(0)" ::: "memory");  // Ml writes drained before first barrier

  f32x4 oacc[2][4];
  float mrun[2], lrun[2];
  const f32x4 vz = {0.f, 0.f, 0.f, 0.f};
  #pragma unroll
  for (int mq = 0; mq < 2; mq++){
    #pragma unroll
    for (int nd = 0; nd < 4; nd++) oacc[mq][nd] = vz;
    mrun[mq] = -1e30f; lrun[mq] = 0.f;
  }

  const int cs0 = (g*8) ^ ((c & 7) << 3);          // swizzled read col, ki=0
  const int cs1 = (32 + g*8) ^ ((c & 7) << 3);     // swizzled read col, ki=1

  for (int t = 0; t < 32; ++t){
    // stage tile t+1 into buf (t+1)&1  (t=31 over-stage is harmless, in-ws)
    gload16(gK + (size_t)(t+1) * 64 * 64, &Kl[(t+1)&1][w*8][0]);
    gload16(gV + (size_t)(t+1) * 64,      &Vl[(t+1)&1][w*8][0]);
    asm volatile("s_waitcnt vmcnt(2)" ::: "memory");  // tile t drained; t+1 in flight
    __builtin_amdgcn_s_barrier();
    asm volatile("" ::: "memory");

    const u16* Kb = &Kl[t&1][0][0];
    const u16* Vb = &Vl[t&1][0][0];
    const int t0 = t * 64;

    // S^T = K (A) x Q (B): sacc[nt][mq] = S[q=qw+mq*16+c][stored t = t0+nt*16+4g+r]
    f32x4 sacc[4][2];
    #pragma unroll
    for (int nt = 0; nt < 4; nt++){ sacc[nt][0] = vz; sacc[nt][1] = vz; }
    #pragma unroll
    for (int ki = 0; ki < 2; ki++){
      const int cs = ki ? cs1 : cs0;
      short8 ka[4];
      #pragma unroll
      for (int nt = 0; nt < 4; nt++) ka[nt] = *(const short8*)&Kb[(nt*16 + c)*64 + cs];
      #pragma unroll
      for (int nt = 0; nt < 4; nt++)
        #pragma unroll
        for (int mq = 0; mq < 2; mq++)
          sacc[nt][mq] = mfma16(ka[nt], qb[mq][ki], sacc[nt][mq]);
    }

    // mask (u8): logical t of (nt,g,r) = t0 + 32*(nt>>1) + 8g + 4*(nt&1) + r
    {
      const u32 mw0 = *(const u32*)&Ml[t0 + 8*g];
      const u32 mw1 = *(const u32*)&Ml[t0 + 8*g + 4];
      const u32 mw2 = *(const u32*)&Ml[t0 + 32 + 8*g];
      const u32 mw3 = *(const u32*)&Ml[t0 + 32 + 8*g + 4];
      if (!__all((mw0 & mw1 & mw2 & mw3) == 0x01010101u)){
        const u32 mw[4] = {mw0, mw1, mw2, mw3};
        #pragma unroll
        for (int nt = 0; nt < 4; nt++)
          #pragma unroll
          for (int r = 0; r < 4; r++)
            if (((mw[nt] >> (8*r)) & 0xFFu) == 0){ sacc[nt][0][r] = -1e9f; sacc[nt][1][r] = -1e9f; }
      }
    }

    // tile max (tree) per mq, row q = qw + mq*16 + c
    float pm[2];
    #pragma unroll
    for (int mq = 0; mq < 2; mq++){
      float a0 = fmaxf(fmaxf(sacc[0][mq][0], sacc[0][mq][1]), fmaxf(sacc[0][mq][2], sacc[0][mq][3]));
      float a1 = fmaxf(fmaxf(sacc[1][mq][0], sacc[1][mq][1]), fmaxf(sacc[1][mq][2], sacc[1][mq][3]));
      float a2 = fmaxf(fmaxf(sacc[2][mq][0], sacc[2][mq][1]), fmaxf(sacc[2][mq][2], sacc[2][mq][3]));
      float a3 = fmaxf(fmaxf(sacc[3][mq][0], sacc[3][mq][1]), fmaxf(sacc[3][mq][2], sacc[3][mq][3]));
      float mm = fmaxf(fmaxf(a0, a1), fmaxf(a2, a3));
      mm = fmaxf(mm, __shfl_xor(mm, 16, 64));
      mm = fmaxf(mm, __shfl_xor(mm, 32, 64));
      pm[mq] = mm;
    }

    // defer-max: rescale only when max grew by > 8 (skip is EXACT when pm<=mrun)
    if (__any((pm[0] > mrun[0] + 8.f) | (pm[1] > mrun[1] + 8.f))){
      float al[2];
      #pragma unroll
      for (int mq = 0; mq < 2; mq++){
        float mn = fmaxf(mrun[mq], pm[mq]);
        al[mq] = exp2f((mrun[mq] - mn) * LOG2E);
        mrun[mq] = mn;
        lrun[mq] *= al[mq];                   // per-lane partial, al row-uniform
      }
      #pragma unroll
      for (int mq = 0; mq < 2; mq++){
        float b0 = __shfl(al[mq], g*4 + 0, 64);
        float b1 = __shfl(al[mq], g*4 + 1, 64);
        float b2 = __shfl(al[mq], g*4 + 2, 64);
        float b3 = __shfl(al[mq], g*4 + 3, 64);
        #pragma unroll
        for (int nd = 0; nd < 4; nd++){
          oacc[mq][nd][0] *= b0; oacc[mq][nd][1] *= b1;
          oacc[mq][nd][2] *= b2; oacc[mq][nd][3] *= b3;
        }
      }
    }

    // P = exp2((s-m)*log2e): RTNE for PV, tree-sum unrounded into per-lane l
    short8 pa[2][2];
    #pragma unroll
    for (int mq = 0; mq < 2; mq++){
      const float nm = -mrun[mq] * LOG2E;
      float p[16]; u32 rb[16];
      #pragma unroll
      for (int nt = 0; nt < 4; nt++)
        #pragma unroll
        for (int r = 0; r < 4; r++){
          float pp = exp2f(fmaf(sacc[nt][mq][r], LOG2E, nm));
          p[nt*4 + r] = pp;
          u32 u = __builtin_bit_cast(u32, pp);
          rb[nt*4 + r] = u + 0x7FFFu + ((u >> 16) & 1u);   // RTNE in bytes 2,3
        }
      float s0 = (p[0] + p[1]) + (p[2] + p[3]);
      float s1 = (p[4] + p[5]) + (p[6] + p[7]);
      float s2 = (p[8] + p[9]) + (p[10] + p[11]);
      float s3 = (p[12] + p[13]) + (p[14] + p[15]);
      lrun[mq] += (s0 + s1) + (s2 + s3);
      u32x4 q0 = { __builtin_amdgcn_perm(rb[1],  rb[0],  0x07060302u),
                   __builtin_amdgcn_perm(rb[3],  rb[2],  0x07060302u),
                   __builtin_amdgcn_perm(rb[5],  rb[4],  0x07060302u),
                   __builtin_amdgcn_perm(rb[7],  rb[6],  0x07060302u) };
      u32x4 q1 = { __builtin_amdgcn_perm(rb[9],  rb[8],  0x07060302u),
                   __builtin_amdgcn_perm(rb[11], rb[10], 0x07060302u),
                   __builtin_amdgcn_perm(rb[13], rb[12], 0x07060302u),
                   __builtin_amdgcn_perm(rb[15], rb[14], 0x07060302u) };
      pa[mq][0] = __builtin_bit_cast(short8, q0);
      pa[mq][1] = __builtin_bit_cast(short8, q1);
    }

    // O += P (A) x V (B)
    #pragma unroll
    for (int ki = 0; ki < 2; ki++){
      const int cs = ki ? cs1 : cs0;
      short8 va[4];
      #pragma unroll
      for (int nd = 0; nd < 4; nd++) va[nd] = *(const short8*)&Vb[(nd*16 + c)*64 + cs];
      #pragma unroll
      for (int mq = 0; mq < 2; mq++)
        #pragma unroll
        for (int nd = 0; nd < 4; nd++)
          oacc[mq][nd] = mfma16(pa[mq][ki], va[nd], oacc[mq][nd]);
    }

    asm volatile("" ::: "memory");
    __builtin_amdgcn_s_barrier();
    asm volatile("" ::: "memory");
  }

  // epilogue: reduce per-lane l partials once; O rows q = qw + mq*16 + 4g + r
  #pragma unroll
  for (int mq = 0; mq < 2; mq++){
    lrun[mq] += __shfl_xor(lrun[mq], 16, 64);
    lrun[mq] += __shfl_xor(lrun[mq], 32, 64);
    #pragma unroll
    for (int r = 0; r < 4; r++){
      float li = __shfl(lrun[mq], g*4 + r, 64);
      float inv = 1.0f / li;
      int q = qw + mq*16 + g*4 + r;
      size_t base = ((size_t)b*2048 + q)*1024 + h*64;
      #pragma unroll
      for (int nd = 0; nd < 4; nd++)
        AO[base + nd*16 + c] = f2bf(oacc[mq][nd][r] * inv);
    }
  }
}

extern "C" void kernel_launch(void* const* d_in, const int* in_sizes, int n_in,
                              void* d_out, int out_size, void* d_ws, size_t ws_size,
                              hipStream_t stream)
{
  const float* x  = (const float*)d_in[0];
  const int* mask = (const int*)d_in[1];
  const float* Wq = (const float*)d_in[2];
  const float* bq = (const float*)d_in[3];
  const float* Wk = (const float*)d_in[4];
  const float* bk = (const float*)d_in[5];
  const float* Wv = (const float*)d_in[6];
  const float* bv = (const float*)d_in[7];
  const float* Wo = (const float*)d_in[8];
  const float* bo = (const float*)d_in[9];
  float* out = (float*)d_out;
  (void)in_sizes; (void)n_in; (void)out_size; (void)ws_size;

  char* ws = (char*)d_ws;
  size_t off = 0;
  auto alloc = [&](size_t bytes){ void* p = ws + off; off += (bytes + 255) & ~(size_t)255; return p; };
  u16* xb    = (u16*)alloc((size_t)8192 * 1024 * 2);
  u16* WT    = (u16*)alloc((size_t)4 * 1024 * 1024 * 2);
  float* cosT = (float*)alloc((size_t)2048 * 32 * 4);
  float* sinT = (float*)alloc((size_t)2048 * 32 * 4);
  u16* Qr    = (u16*)alloc((size_t)8192 * 1024 * 2);
  u16* Kr    = (u16*)alloc((size_t)8192 * 1024 * 2);
  u16* Vt    = (u16*)alloc((size_t)8192 * 1024 * 2);
  u16* AO    = (u16*)alloc((size_t)8192 * 1024 * 2);

  rope_tab_k<<<dim3(256), dim3(256), 0, stream>>>(cosT, sinT);
  cvt_x_k<<<dim3(8192), dim3(256), 0, stream>>>(x, xb, 8192 * 1024);
  wt_cvt_k<<<dim3(32, 32, 4), dim3(32, 8), 0, stream>>>(Wq, Wk, Wv, Wo, WT);

  qkv_gemm_k<<<dim3(64, 24), dim3(256), 0, stream>>>(xb, WT, bq, bk, bv, cosT, sinT, Qr, Kr, Vt);

  attn_fwd_k<<<dim3(8, 64), dim3(512), 0, stream>>>(Qr, Kr, Vt, mask, AO);

  out_gemm_k<<<dim3(64, 8), dim3(256), 0, stream>>>(AO, WT + 3*1024*1024, bo, out);
}